// Round 18
// baseline (8125.638 us; speedup 1.0000x reference)
//
#include <hip/hip_runtime.h>

typedef unsigned short ushort_t;
typedef unsigned int uint_t;

using f16x8 = __attribute__((ext_vector_type(8))) _Float16;
using f32x4 = __attribute__((ext_vector_type(4))) float;
using u32x4 = __attribute__((ext_vector_type(4))) unsigned int;

#define BATCH 64
#define SEQT 512
#define DIN 256
#define HID 256
#define G4 1024   // 4*HID
#define CH 16     // pipeline chunk (timesteps)
#define NCH (SEQT / CH)

static __device__ __forceinline__ ushort_t f16b(float x) {
    return __builtin_bit_cast(ushort_t, (_Float16)x);
}
static __device__ __forceinline__ float f16f(ushort_t u) {
    return (float)__builtin_bit_cast(_Float16, u);
}
static __device__ __forceinline__ uint_t pk2(float a, float b) {
    return (uint_t)f16b(a) | ((uint_t)f16b(b) << 16);
}
static __device__ __forceinline__ float sig_(float x) {
    return 1.f / (1.f + __expf(-x));
}
static __device__ __forceinline__ float tanh_(float x) {
    float e = __expf(2.f * x);
    return (e - 1.f) / (e + 1.f);
}

#define PINA(x) asm volatile("" : "+a"(x))
#define PINV(x) asm volatile("" : "+v"(x))

static __device__ __forceinline__ f16x8 asf16(u32x4 v) {
    return __builtin_bit_cast(f16x8, v);
}

// ---------------- merged prep kernel ----------------

__global__ void prep_all_kernel(
    const float* __restrict__ x,
    const float* __restrict__ W0, const float* __restrict__ W1,
    const float* __restrict__ U0, const float* __restrict__ U1,
    ushort_t* __restrict__ xf16,
    ushort_t* __restrict__ Wt0, ushort_t* __restrict__ Wt1,
    uint4* __restrict__ Upk0, uint4* __restrict__ Upk1)
{
    int blk = blockIdx.x;
    int tid = threadIdx.x;
    if (blk < 8192) {
        int i = blk * 256 + tid;
        float4 v = ((const float4*)x)[i];
        ushort4 o;
        o.x = f16b(v.x); o.y = f16b(v.y); o.z = f16b(v.z); o.w = f16b(v.w);
        ((ushort4*)xf16)[i] = o;
    } else if (blk < 10240) {
        const float* W = (blk < 9216) ? W0 : W1;
        ushort_t* Wt = (blk < 9216) ? Wt0 : Wt1;
        int t = ((blk - 8192) & 1023) * 256 + tid;
        int k = t >> 10;
        int n = t & 1023;
        Wt[n * DIN + k] = f16b(W[t]);
    } else {
        const float* U = (blk < 10368) ? U0 : U1;
        uint4* Upk = (blk < 10368) ? Upk0 : Upk1;
        int t = ((blk - 10240) & 127) * 256 + tid;
        int j = t >> 10;
        int g = t & 1023;
        uint4 o;
        uint_t* op = &o.x;
#pragma unroll
        for (int q = 0; q < 4; ++q) {
            float a = U[(8 * j + 2 * q) * G4 + g];
            float bb = U[(8 * j + 2 * q + 1) * G4 + g];
            op[q] = pk2(a, bb);
        }
        Upk[t] = o;
    }
}

// ---------------- GEMM1 (layer-1 input projection; f16 output) ----------------

#define GSTRIDE 40

__global__ __launch_bounds__(256) void gemm_f16_kernel(
    const ushort_t* __restrict__ A,
    const ushort_t* __restrict__ Bt,
    const float* __restrict__ bias,
    ushort_t* __restrict__ C,
    int M)
{
    const int K = DIN, N = G4;
    __shared__ ushort_t As[128 * GSTRIDE];
    __shared__ ushort_t Bs[128 * GSTRIDE];
    int tid = threadIdx.x;
    int bx = blockIdx.x & 7;
    int by = blockIdx.x >> 3;
    int m0 = by * 128, n0 = bx * 128;
    int w = tid >> 6, lane = tid & 63;
    int wr = (w >> 1) * 64, wc = (w & 1) * 64;
    int r = lane & 15, kg = lane >> 4;

    f32x4 acc[4][4];
#pragma unroll
    for (int i = 0; i < 4; ++i)
#pragma unroll
        for (int j = 0; j < 4; ++j)
            acc[i][j] = f32x4{0.f, 0.f, 0.f, 0.f};

    for (int kt = 0; kt < K; kt += 32) {
        __syncthreads();
#pragma unroll
        for (int s = 0; s < 2; ++s) {
            int chunk = tid + s * 256;
            int row = chunk >> 2;
            int ko = (chunk & 3) * 8;
            uint4 va = *(const uint4*)(A + (size_t)(m0 + row) * K + kt + ko);
            *(uint4*)(&As[row * GSTRIDE + ko]) = va;
            uint4 vb = *(const uint4*)(Bt + (size_t)(n0 + row) * K + kt + ko);
            *(uint4*)(&Bs[row * GSTRIDE + ko]) = vb;
        }
        __syncthreads();
        f16x8 af[4], bf[4];
#pragma unroll
        for (int i = 0; i < 4; ++i) {
            af[i] = *(const f16x8*)(&As[(wr + i * 16 + r) * GSTRIDE + kg * 8]);
            bf[i] = *(const f16x8*)(&Bs[(wc + i * 16 + r) * GSTRIDE + kg * 8]);
        }
#pragma unroll
        for (int i = 0; i < 4; ++i)
#pragma unroll
            for (int j = 0; j < 4; ++j)
                acc[i][j] = __builtin_amdgcn_mfma_f32_16x16x32_f16(af[i], bf[j], acc[i][j], 0, 0, 0);
    }

#pragma unroll
    for (int i = 0; i < 4; ++i)
#pragma unroll
        for (int j = 0; j < 4; ++j) {
            int col = n0 + wc + j * 16 + r;
            float bv = bias[col];
#pragma unroll
            for (int v = 0; v < 4; ++v) {
                int rowg = m0 + wr + i * 16 + kg * 4 + v;
                C[(size_t)rowg * N + col] = f16b(acc[i][j][v] + bv);
            }
        }
}

// ---------------- 3-stage pipeline, 2 batch rows per rec WG ----------------
// Grid 128. blk 0-31: producer pair pr (rows 2pr,2pr+1) — per iteration:
// STEP(A) tail(A) STEP(B) tail(B) barrier. A's VALU tail hides under B's
// MFMA pipe time (separate pipes). One barrier + one h-exchange per 2 steps.
// blk 32-95: GEMM2 (row b = blk-32): y1 chunk @ Wt1 + b1 -> xz2u ring.
// blk 96-127: consumer pair: same 2-row interleave; direct out stores.

__global__ __launch_bounds__(256)
__attribute__((amdgpu_waves_per_eu(1, 1)))
void lstm_pipe3_kernel(
    const ushort_t* __restrict__ xz1h,  // [B*T][1024] f16 (bias incl)
    const u32x4* __restrict__ Upk0,     // [32][1024]
    const u32x4* __restrict__ Upk1,     // [32][1024]
    const ushort_t* __restrict__ Wt1,   // [1024][256] f16
    const float* __restrict__ b1,       // [1024]
    uint_t* y1pk,                       // [B*T][128] packed h1
    int* flag1, int* flag2, int* flag3, // flag1: [32 pairs], flag2/3: [64 rows]
    uint_t* xz2u,                       // [B][4][CH][1024] f32-bits ring
    float* __restrict__ out,            // [B*T][256]
    int T)
{
    __shared__ __align__(16) u32x4 Uld[4][2][16][64];   // 128 KB
    __shared__ __align__(16) ushort_t ys[32][264];      // 16.5 KB (A-stage / h-rings)
    __shared__ __align__(16) ushort_t h16[2][2][HID];   // 2 KB [row][buf]

    const int tid = threadIdx.x;
    const int w = tid >> 6;
    const int l = tid & 63;
    const int lg = l >> 4;
    const int lr = l & 15;
    const int blk = (int)blockIdx.x;
    const int hcol = w * 64 + lg * 16 + lr;

    int role, pr = 0, grow = 0;
    if (blk < 32)       { role = 0; pr = blk; }
    else if (blk < 96)  { role = 1; grow = blk - 32; }
    else                { role = 2; pr = blk - 96; }

    if (role == 1) {
        // ================= GEMM2 stage (row grow, M=16 per chunk) =================
        int* f1p = flag1 + (grow >> 1) * 32;
        int* f2p = flag2 + grow * 32;
        int* f3p = flag3 + grow * 32;
        float b1w[16];
#pragma unroll
        for (int ct = 0; ct < 16; ++ct) b1w[ct] = b1[(w * 16 + ct) * 16 + lr];
        __syncthreads();

        for (int ch = 0; ch < NCH; ++ch) {
            if (tid == 0) {
                while (__hip_atomic_load(f1p, __ATOMIC_ACQUIRE, __HIP_MEMORY_SCOPE_AGENT) < ch + 1)
                    __builtin_amdgcn_s_sleep(32);
                while (__hip_atomic_load(f3p, __ATOMIC_ACQUIRE, __HIP_MEMORY_SCOPE_AGENT) < ch - 3)
                    __builtin_amdgcn_s_sleep(32);
            }
            __syncthreads();

#pragma unroll
            for (int it = 0; it < 8; ++it) {
                int idx = it * 256 + tid;
                int row = idx >> 7;
                int j = idx & 127;
                uint_t v = __hip_atomic_load(
                    &y1pk[(size_t)(grow * T + ch * CH + row) * 128 + j],
                    __ATOMIC_RELAXED, __HIP_MEMORY_SCOPE_AGENT);
                *(uint_t*)&ys[row][2 * j] = v;
            }
            __syncthreads();

            uint_t* xzbuf = xz2u + ((size_t)(grow * 4 + (ch & 3)) * CH) * G4;
#pragma unroll
            for (int ct = 0; ct < 16; ++ct) {
                int ctI = w * 16 + ct;
                u32x4 bf[8];
#pragma unroll
                for (int kt = 0; kt < 8; ++kt)
                    bf[kt] = *(const u32x4*)(Wt1 + (size_t)(ctI * 16 + lr) * DIN + kt * 32 + lg * 8);
                f32x4 acc = f32x4{0.f, 0.f, 0.f, 0.f};
#pragma unroll
                for (int kt = 0; kt < 8; ++kt) {
                    f16x8 af = *(const f16x8*)&ys[lr][kt * 32 + lg * 8];
                    acc = __builtin_amdgcn_mfma_f32_16x16x32_f16(af, asf16(bf[kt]), acc, 0, 0, 0);
                }
#pragma unroll
                for (int v = 0; v < 4; ++v) {
                    float z = acc[v] + b1w[ct];
                    __hip_atomic_store(&xzbuf[(size_t)(lg * 4 + v) * G4 + ctI * 16 + lr],
                                       __builtin_bit_cast(uint_t, z),
                                       __ATOMIC_RELAXED, __HIP_MEMORY_SCOPE_AGENT);
                }
            }
            __syncthreads();
            if (tid == 0)
                __hip_atomic_store(f2p, ch + 1, __ATOMIC_RELEASE, __HIP_MEMORY_SCOPE_AGENT);
        }
        return;
    }

    // ---- roles 0,2: rows r0,r1; preload U fragments (r7 layout) ----
    const int r0 = pr * 2, r1 = pr * 2 + 1;
    const u32x4* Upk = (role == 2) ? Upk1 : Upk0;
    u32x4 ua[64];   // kt0-3 -> AGPR
    u32x4 uv[32];   // kt4-5 -> VGPR
#pragma unroll
    for (int gb = 0; gb < 4; ++gb)
#pragma unroll
        for (int ti = 0; ti < 4; ++ti) {
            int col = (gb * 16 + w * 4 + ti) * 16 + lr;
            int fi = gb * 4 + ti;
#pragma unroll
            for (int kt = 0; kt < 4; ++kt)
                ua[fi * 4 + kt] = Upk[(kt * 4 + lg) * 1024 + col];
#pragma unroll
            for (int k2 = 0; k2 < 2; ++k2)
                uv[fi * 2 + k2] = Upk[((4 + k2) * 4 + lg) * 1024 + col];
        }
#pragma unroll
    for (int i = 0; i < 64; ++i) PINA(ua[i]);
#pragma unroll
    for (int i = 0; i < 32; ++i) PINV(uv[i]);

#pragma unroll
    for (int gb = 0; gb < 4; ++gb)
#pragma unroll
        for (int ti = 0; ti < 4; ++ti) {
            int col = (gb * 16 + w * 4 + ti) * 16 + lr;
            int fi = gb * 4 + ti;
#pragma unroll
            for (int k2 = 0; k2 < 2; ++k2)
                Uld[w][k2][fi][l] = Upk[((6 + k2) * 4 + lg) * 1024 + col];
        }

    h16[0][0][tid] = 0;
    h16[1][0][tid] = 0;
    float cA = 0.f, cB = 0.f;

#define STEP_BODY(AF, XZC, ZG)                                                        \
    {                                                                                 \
        _Pragma("unroll")                                                             \
        for (int gb = 0; gb < 4; ++gb) {                                              \
            f32x4 accA[4], accB[4];                                                   \
            _Pragma("unroll")                                                         \
            for (int ti = 0; ti < 4; ++ti) {                                          \
                accA[ti] = f32x4{0.f, 0.f, 0.f, 0.f};                                 \
                accB[ti] = f32x4{0.f, 0.f, 0.f, 0.f};                                 \
            }                                                                         \
            _Pragma("unroll")                                                         \
            for (int ti = 0; ti < 4; ++ti) {                                          \
                int fi = gb * 4 + ti;                                                 \
                _Pragma("unroll")                                                     \
                for (int kt = 0; kt < 4; ++kt)                                        \
                    accA[ti] = __builtin_amdgcn_mfma_f32_16x16x32_f16(                \
                        AF[kt], asf16(ua[fi * 4 + kt]), accA[ti], 0, 0, 0);           \
                _Pragma("unroll")                                                     \
                for (int k2 = 0; k2 < 2; ++k2)                                        \
                    accB[ti] = __builtin_amdgcn_mfma_f32_16x16x32_f16(                \
                        AF[4 + k2], asf16(uv[fi * 2 + k2]), accB[ti], 0, 0, 0);       \
                _Pragma("unroll")                                                     \
                for (int k2 = 0; k2 < 2; ++k2) {                                      \
                    u32x4 ub = Uld[w][k2][fi][l];                                     \
                    accB[ti] = __builtin_amdgcn_mfma_f32_16x16x32_f16(                \
                        AF[6 + k2], asf16(ub), accB[ti], 0, 0, 0);                    \
                }                                                                     \
            }                                                                         \
            float za = (lg == 0) ? accA[0][0] : (lg == 1) ? accA[1][0]                \
                     : (lg == 2) ? accA[2][0] : accA[3][0];                           \
            float zb = (lg == 0) ? accB[0][0] : (lg == 1) ? accB[1][0]                \
                     : (lg == 2) ? accB[2][0] : accB[3][0];                           \
            ZG[gb] = za + zb + XZC[gb];                                               \
        }                                                                             \
    }

    if (role == 0) {
        // ================= layer-1 producer (2 rows) =================
        int* f1p = flag1 + pr * 32;
        uint_t* hrA = (uint_t*)&ys[0][0];          // [CH][128] (8 KB)
        uint_t* hrB = hrA + CH * 128;              // (8 KB)
        const ushort_t* xzbA = xz1h + (size_t)r0 * T * G4;
        const ushort_t* xzbB = xz1h + (size_t)r1 * T * G4;
        float xzcA[4], xzcB[4];
#pragma unroll
        for (int gb = 0; gb < 4; ++gb) {
            xzcA[gb] = f16f(xzbA[gb * 256 + hcol]);
            xzcB[gb] = f16f(xzbB[gb * 256 + hcol]);
        }
        __syncthreads();

        for (int t = 0; t < T; ++t) {
            const int cur = t & 1, nxt = cur ^ 1;
            int tn = (t + 1 < T) ? (t + 1) : t;

            // row A step
            f16x8 afA[8];
#pragma unroll
            for (int kt = 0; kt < 8; ++kt)
                afA[kt] = *(const f16x8*)((const char*)&h16[0][cur][0] + kt * 64 + lg * 16);
            float xznA[4];
#pragma unroll
            for (int gb = 0; gb < 4; ++gb)
                xznA[gb] = f16f(xzbA[(size_t)tn * G4 + gb * 256 + hcol]);
            float zgA[4];
            STEP_BODY(afA, xzcA, zgA);
            cA = sig_(zgA[1]) * cA + sig_(zgA[0]) * tanh_(zgA[2]);
            float hA = sig_(zgA[3]) * tanh_(cA);
            h16[0][nxt][hcol] = f16b(hA);
            {
                uint_t hb = (uint_t)f16b(hA);
                uint_t pb = (uint_t)(unsigned)__shfl_xor((int)hb, 1);
                if (!(l & 1)) hrA[(t & (CH - 1)) * 128 + (hcol >> 1)] = hb | (pb << 16);
            }
#pragma unroll
            for (int gb = 0; gb < 4; ++gb) xzcA[gb] = xznA[gb];

            // row B step (independent: MFMAs overlap A's tail)
            f16x8 afB[8];
#pragma unroll
            for (int kt = 0; kt < 8; ++kt)
                afB[kt] = *(const f16x8*)((const char*)&h16[1][cur][0] + kt * 64 + lg * 16);
            float xznB[4];
#pragma unroll
            for (int gb = 0; gb < 4; ++gb)
                xznB[gb] = f16f(xzbB[(size_t)tn * G4 + gb * 256 + hcol]);
            float zgB[4];
            STEP_BODY(afB, xzcB, zgB);
            cB = sig_(zgB[1]) * cB + sig_(zgB[0]) * tanh_(zgB[2]);
            float hB = sig_(zgB[3]) * tanh_(cB);
            h16[1][nxt][hcol] = f16b(hB);
            {
                uint_t hb = (uint_t)f16b(hB);
                uint_t pb = (uint_t)(unsigned)__shfl_xor((int)hb, 1);
                if (!(l & 1)) hrB[(t & (CH - 1)) * 128 + (hcol >> 1)] = hb | (pb << 16);
            }
#pragma unroll
            for (int gb = 0; gb < 4; ++gb) xzcB[gb] = xznB[gb];

            __syncthreads();

            if ((t & (CH - 1)) == (CH - 1)) {
                int t0 = t - (CH - 1);
#pragma unroll
                for (int it = 0; it < 8; ++it) {
                    int idx = it * 256 + tid;
                    int row = idx >> 7;
                    int j = idx & 127;
                    __hip_atomic_store(&y1pk[(size_t)(r0 * T + t0 + row) * 128 + j],
                                       hrA[row * 128 + j],
                                       __ATOMIC_RELAXED, __HIP_MEMORY_SCOPE_AGENT);
                    __hip_atomic_store(&y1pk[(size_t)(r1 * T + t0 + row) * 128 + j],
                                       hrB[row * 128 + j],
                                       __ATOMIC_RELAXED, __HIP_MEMORY_SCOPE_AGENT);
                }
                __syncthreads();
                if (tid == 0)
                    __hip_atomic_store(f1p, (t + 1) / CH, __ATOMIC_RELEASE,
                                       __HIP_MEMORY_SCOPE_AGENT);
            }
        }
    } else {
        // ================= layer-2 consumer (2 rows) =================
        int* f2p0 = flag2 + r0 * 32;
        int* f2p1 = flag2 + r1 * 32;
        int* f3p0 = flag3 + r0 * 32;
        int* f3p1 = flag3 + r1 * 32;
        size_t obA = (size_t)r0 * T * HID + hcol;
        size_t obB = (size_t)r1 * T * HID + hcol;
        __syncthreads();

        for (int ch = 0; ch < NCH; ++ch) {
            if (tid == 0) {
                while (__hip_atomic_load(f2p0, __ATOMIC_ACQUIRE, __HIP_MEMORY_SCOPE_AGENT) < ch + 1)
                    __builtin_amdgcn_s_sleep(32);
                while (__hip_atomic_load(f2p1, __ATOMIC_ACQUIRE, __HIP_MEMORY_SCOPE_AGENT) < ch + 1)
                    __builtin_amdgcn_s_sleep(32);
            }
            __syncthreads();

            const uint_t* xzbufA = xz2u + ((size_t)(r0 * 4 + (ch & 3)) * CH) * G4;
            const uint_t* xzbufB = xz2u + ((size_t)(r1 * 4 + (ch & 3)) * CH) * G4;
            uint_t xzwA[4], xznwA[4], xzwB[4], xznwB[4];

            for (int tb = 0; tb < CH; ++tb) {
                const int t = ch * CH + tb;
                const int cur = t & 1, nxt = cur ^ 1;

                if (tb == 0) {
#pragma unroll
                    for (int gb = 0; gb < 4; ++gb) {
                        xzwA[gb] = __hip_atomic_load(&xzbufA[gb * 256 + hcol],
                                                     __ATOMIC_RELAXED, __HIP_MEMORY_SCOPE_AGENT);
                        xzwB[gb] = __hip_atomic_load(&xzbufB[gb * 256 + hcol],
                                                     __ATOMIC_RELAXED, __HIP_MEMORY_SCOPE_AGENT);
                    }
                } else {
#pragma unroll
                    for (int gb = 0; gb < 4; ++gb) { xzwA[gb] = xznwA[gb]; xzwB[gb] = xznwB[gb]; }
                }
                if (tb + 1 < CH) {
#pragma unroll
                    for (int gb = 0; gb < 4; ++gb) {
                        xznwA[gb] = __hip_atomic_load(
                            &xzbufA[(size_t)(tb + 1) * G4 + gb * 256 + hcol],
                            __ATOMIC_RELAXED, __HIP_MEMORY_SCOPE_AGENT);
                        xznwB[gb] = __hip_atomic_load(
                            &xzbufB[(size_t)(tb + 1) * G4 + gb * 256 + hcol],
                            __ATOMIC_RELAXED, __HIP_MEMORY_SCOPE_AGENT);
                    }
                }

                // row A step
                f16x8 afA[8];
#pragma unroll
                for (int kt = 0; kt < 8; ++kt)
                    afA[kt] = *(const f16x8*)((const char*)&h16[0][cur][0] + kt * 64 + lg * 16);
                float xzcA[4];
#pragma unroll
                for (int gb = 0; gb < 4; ++gb) xzcA[gb] = __builtin_bit_cast(float, xzwA[gb]);
                float zgA[4];
                STEP_BODY(afA, xzcA, zgA);
                cA = sig_(zgA[1]) * cA + sig_(zgA[0]) * tanh_(zgA[2]);
                float hA = sig_(zgA[3]) * tanh_(cA);
                h16[0][nxt][hcol] = f16b(hA);
                out[obA] = hA;
                obA += HID;

                // row B step
                f16x8 afB[8];
#pragma unroll
                for (int kt = 0; kt < 8; ++kt)
                    afB[kt] = *(const f16x8*)((const char*)&h16[1][cur][0] + kt * 64 + lg * 16);
                float xzcB[4];
#pragma unroll
                for (int gb = 0; gb < 4; ++gb) xzcB[gb] = __builtin_bit_cast(float, xzwB[gb]);
                float zgB[4];
                STEP_BODY(afB, xzcB, zgB);
                cB = sig_(zgB[1]) * cB + sig_(zgB[0]) * tanh_(zgB[2]);
                float hB = sig_(zgB[3]) * tanh_(cB);
                h16[1][nxt][hcol] = f16b(hB);
                out[obB] = hB;
                obB += HID;

                __syncthreads();
            }
            if (tid == 0) {
                __hip_atomic_store(f3p0, ch + 1, __ATOMIC_RELEASE, __HIP_MEMORY_SCOPE_AGENT);
                __hip_atomic_store(f3p1, ch + 1, __ATOMIC_RELEASE, __HIP_MEMORY_SCOPE_AGENT);
            }
        }
    }
#undef STEP_BODY
}

// ---------------- launch ----------------

extern "C" void kernel_launch(void* const* d_in, const int* in_sizes, int n_in,
                              void* d_out, int out_size, void* d_ws, size_t ws_size,
                              hipStream_t stream) {
    const float* x  = (const float*)d_in[0];
    const float* W0 = (const float*)d_in[1];
    const float* U0 = (const float*)d_in[2];
    const float* b0 = (const float*)d_in[3];
    const float* W1 = (const float*)d_in[4];
    const float* U1 = (const float*)d_in[5];
    const float* b1 = (const float*)d_in[6];
    float* out = (float*)d_out;

    const size_t M = (size_t)BATCH * SEQT;   // 32768

    char* ws = (char*)d_ws;
    ushort_t* xf16  = (ushort_t*)(ws);                         // 16 MB @ 0
    uint_t*   y1pk  = (uint_t*)  (ws + (16u << 20));           // 16 MB @ 16M
    ushort_t* Wt0   = (ushort_t*)(ws + (32u << 20));           // 0.5 MB @ 32M
    ushort_t* Wt1   = (ushort_t*)(ws + (32u << 20) + 524288);  // 0.5 MB
    u32x4*    Upk0  = (u32x4*)   (ws + (33u << 20));           // 0.5 MB @ 33M
    u32x4*    Upk1  = (u32x4*)   (ws + (33u << 20) + 524288);  // 0.5 MB
    int*      flag1 = (int*)     (ws + (34u << 20));           // @34M
    int*      flag2 = (int*)     (ws + (34u << 20) + 65536);
    int*      flag3 = (int*)     (ws + (34u << 20) + 131072);
    uint_t*   xz2u  = (uint_t*)  (ws + (35u << 20));           // 16 MB @ 35M
    ushort_t* xz1h  = (ushort_t*)(ws + (51u << 20));           // 64 MB @ 51M

    // reset handoff flags every launch (graph-replay safe)
    hipMemsetAsync(flag1, 0, 196608, stream);

    // merged prep: cvt_x + Wt0/Wt1 + Upk0/Upk1 (one launch)
    prep_all_kernel<<<dim3(10496), dim3(256), 0, stream>>>(
        x, W0, W1, U0, U1, xf16, Wt0, Wt1, (uint4*)Upk0, (uint4*)Upk1);

    // layer-1 input projection (f16 output)
    gemm_f16_kernel<<<dim3((int)(M / 128) * 8), dim3(256), 0, stream>>>(xf16, Wt0, b0, xz1h, (int)M);

    // 3-stage pipeline: 32 producer pairs + 64 gemm + 32 consumer pairs
    lstm_pipe3_kernel<<<dim3(128), dim3(256), 0, stream>>>(
        xz1h, Upk0, Upk1, Wt1, b1, y1pk, flag1, flag2, flag3, xz2u, out, SEQT);
}

// Round 19
// 1119.868 us; speedup vs baseline: 7.2559x; 7.2559x over previous
//
#include <hip/hip_runtime.h>

typedef unsigned short ushort_t;
typedef unsigned int uint_t;

using f16x8 = __attribute__((ext_vector_type(8))) _Float16;
using f32x4 = __attribute__((ext_vector_type(4))) float;
using u32x4 = __attribute__((ext_vector_type(4))) unsigned int;

#define BATCH 64
#define SEQT 512
#define DIN 256
#define HID 256
#define G4 1024   // 4*HID
#define CH 16     // pipeline chunk (timesteps)
#define NCH (SEQT / CH)

static __device__ __forceinline__ ushort_t f16b(float x) {
    return __builtin_bit_cast(ushort_t, (_Float16)x);
}
static __device__ __forceinline__ float f16f(ushort_t u) {
    return (float)__builtin_bit_cast(_Float16, u);
}
static __device__ __forceinline__ uint_t pk2(float a, float b) {
    return (uint_t)f16b(a) | ((uint_t)f16b(b) << 16);
}
static __device__ __forceinline__ float sig_(float x) {
    return 1.f / (1.f + __expf(-x));
}
static __device__ __forceinline__ float tanh_(float x) {
    float e = __expf(2.f * x);
    return (e - 1.f) / (e + 1.f);
}

#define PINA(x) asm volatile("" : "+a"(x))
#define PINV(x) asm volatile("" : "+v"(x))

static __device__ __forceinline__ f16x8 asf16(u32x4 v) {
    return __builtin_bit_cast(f16x8, v);
}

// ---------------- merged prep kernel ----------------
// blocks [0,8192): x f32 -> f16; [8192,9216): W0 -> Wt0; [9216,10240): W1 -> Wt1
// [10240,10368): U0 -> Upk0; [10368,10496): U1 -> Upk1

__global__ void prep_all_kernel(
    const float* __restrict__ x,
    const float* __restrict__ W0, const float* __restrict__ W1,
    const float* __restrict__ U0, const float* __restrict__ U1,
    ushort_t* __restrict__ xf16,
    ushort_t* __restrict__ Wt0, ushort_t* __restrict__ Wt1,
    uint4* __restrict__ Upk0, uint4* __restrict__ Upk1)
{
    int blk = blockIdx.x;
    int tid = threadIdx.x;
    if (blk < 8192) {
        int i = blk * 256 + tid;
        float4 v = ((const float4*)x)[i];
        ushort4 o;
        o.x = f16b(v.x); o.y = f16b(v.y); o.z = f16b(v.z); o.w = f16b(v.w);
        ((ushort4*)xf16)[i] = o;
    } else if (blk < 10240) {
        const float* W = (blk < 9216) ? W0 : W1;
        ushort_t* Wt = (blk < 9216) ? Wt0 : Wt1;
        int t = ((blk - 8192) & 1023) * 256 + tid;
        int k = t >> 10;
        int n = t & 1023;
        Wt[n * DIN + k] = f16b(W[t]);
    } else {
        const float* U = (blk < 10368) ? U0 : U1;
        uint4* Upk = (blk < 10368) ? Upk0 : Upk1;
        int t = ((blk - 10240) & 127) * 256 + tid;
        int j = t >> 10;
        int g = t & 1023;
        uint4 o;
        uint_t* op = &o.x;
#pragma unroll
        for (int q = 0; q < 4; ++q) {
            float a = U[(8 * j + 2 * q) * G4 + g];
            float bb = U[(8 * j + 2 * q + 1) * G4 + g];
            op[q] = pk2(a, bb);
        }
        Upk[t] = o;
    }
}

// ---------------- GEMM1 (layer-1 input projection; f16 output) ----------------

#define GSTRIDE 40

__global__ __launch_bounds__(256) void gemm_f16_kernel(
    const ushort_t* __restrict__ A,
    const ushort_t* __restrict__ Bt,
    const float* __restrict__ bias,
    ushort_t* __restrict__ C,         // f16 output
    int M)
{
    const int K = DIN, N = G4;
    __shared__ ushort_t As[128 * GSTRIDE];
    __shared__ ushort_t Bs[128 * GSTRIDE];
    int tid = threadIdx.x;
    int bx = blockIdx.x & 7;
    int by = blockIdx.x >> 3;
    int m0 = by * 128, n0 = bx * 128;
    int w = tid >> 6, lane = tid & 63;
    int wr = (w >> 1) * 64, wc = (w & 1) * 64;
    int r = lane & 15, kg = lane >> 4;

    f32x4 acc[4][4];
#pragma unroll
    for (int i = 0; i < 4; ++i)
#pragma unroll
        for (int j = 0; j < 4; ++j)
            acc[i][j] = f32x4{0.f, 0.f, 0.f, 0.f};

    for (int kt = 0; kt < K; kt += 32) {
        __syncthreads();
#pragma unroll
        for (int s = 0; s < 2; ++s) {
            int chunk = tid + s * 256;
            int row = chunk >> 2;
            int ko = (chunk & 3) * 8;
            uint4 va = *(const uint4*)(A + (size_t)(m0 + row) * K + kt + ko);
            *(uint4*)(&As[row * GSTRIDE + ko]) = va;
            uint4 vb = *(const uint4*)(Bt + (size_t)(n0 + row) * K + kt + ko);
            *(uint4*)(&Bs[row * GSTRIDE + ko]) = vb;
        }
        __syncthreads();
        f16x8 af[4], bf[4];
#pragma unroll
        for (int i = 0; i < 4; ++i) {
            af[i] = *(const f16x8*)(&As[(wr + i * 16 + r) * GSTRIDE + kg * 8]);
            bf[i] = *(const f16x8*)(&Bs[(wc + i * 16 + r) * GSTRIDE + kg * 8]);
        }
#pragma unroll
        for (int i = 0; i < 4; ++i)
#pragma unroll
            for (int j = 0; j < 4; ++j)
                acc[i][j] = __builtin_amdgcn_mfma_f32_16x16x32_f16(af[i], bf[j], acc[i][j], 0, 0, 0);
    }

#pragma unroll
    for (int i = 0; i < 4; ++i)
#pragma unroll
        for (int j = 0; j < 4; ++j) {
            int col = n0 + wc + j * 16 + r;
            float bv = bias[col];
#pragma unroll
            for (int v = 0; v < 4; ++v) {
                int rowg = m0 + wr + i * 16 + kg * 4 + v;
                C[(size_t)rowg * N + col] = f16b(acc[i][j][v] + bv);
            }
        }
}

// ---------------- 3-stage pipelined 2-layer recurrence (r16 final) ----------------
// 192 WGs x 256 thr. Role 0 (blk 0-63): layer-1 producer (r13 body, plain f16
// xz1 loads + prefetch; y1 LDS ring -> y1pk atomics + flag1 per CH=16).
// Role 1 (blk 64-127): GEMM2 stage: y1 chunk (M=16) @ Wt1 + b1 -> xz2u ring
// (4-deep), waits flag1 & flag3, releases flag2.
// Role 2 (blk 128-191): layer-2 consumer: xz2 atomics PREFETCHED one step
// ahead; h -> LDS out-ring, ONE coalesced out dump per chunk; flag3 per chunk.

__global__ __launch_bounds__(256)
__attribute__((amdgpu_waves_per_eu(1, 1)))
void lstm_pipe3_kernel(
    const ushort_t* __restrict__ xz1h,  // [B*T][1024] f16 (bias incl)
    const u32x4* __restrict__ Upk0,     // [32][1024]
    const u32x4* __restrict__ Upk1,     // [32][1024]
    const ushort_t* __restrict__ Wt1,   // [1024][256] f16
    const float* __restrict__ b1,       // [1024]
    uint_t* y1pk,                       // [B*T][128] packed h1
    int* flag1, int* flag2, int* flag3, // [B][32] each (128-B stride)
    uint_t* xz2u,                       // [B][4][CH][1024] f32-bits ring
    float* __restrict__ out,            // [B*T][256]
    int T)
{
    __shared__ __align__(16) u32x4 Uld[4][2][16][64];   // 128 KB
    __shared__ __align__(16) ushort_t ys[32][264];      // 16.5 KB (A-stage / h-ring / out-ring)
    __shared__ __align__(16) ushort_t h16[2][HID];      // 1 KB

    const int tid = threadIdx.x;
    const int w = tid >> 6;
    const int l = tid & 63;
    const int lg = l >> 4;
    const int lr = l & 15;
    const int role = (int)(blockIdx.x >> 6);   // 0 producer, 1 gemm, 2 consumer
    const int b = (int)(blockIdx.x & 63);
    const int hcol = w * 64 + lg * 16 + lr;

    int* f1p = flag1 + b * 32;
    int* f2p = flag2 + b * 32;
    int* f3p = flag3 + b * 32;

    if (role == 1) {
        // ================= GEMM2 stage (M=16 per chunk) =================
        float b1w[16];
#pragma unroll
        for (int ct = 0; ct < 16; ++ct) b1w[ct] = b1[(w * 16 + ct) * 16 + lr];
        __syncthreads();

        for (int ch = 0; ch < NCH; ++ch) {
            if (tid == 0) {
                while (__hip_atomic_load(f1p, __ATOMIC_ACQUIRE, __HIP_MEMORY_SCOPE_AGENT) < ch + 1)
                    __builtin_amdgcn_s_sleep(32);
                while (__hip_atomic_load(f3p, __ATOMIC_ACQUIRE, __HIP_MEMORY_SCOPE_AGENT) < ch - 3)
                    __builtin_amdgcn_s_sleep(32);
            }
            __syncthreads();

            // stage y1 chunk: 16 rows x 128 u32
#pragma unroll
            for (int it = 0; it < 8; ++it) {
                int idx = it * 256 + tid;      // 0..2047
                int row = idx >> 7;
                int j = idx & 127;
                uint_t v = __hip_atomic_load(
                    &y1pk[(size_t)(b * T + ch * CH + row) * 128 + j],
                    __ATOMIC_RELAXED, __HIP_MEMORY_SCOPE_AGENT);
                *(uint_t*)&ys[row][2 * j] = v;
            }
            __syncthreads();

            uint_t* xzbuf = xz2u + ((size_t)(b * 4 + (ch & 3)) * CH) * G4;
#pragma unroll
            for (int ct = 0; ct < 16; ++ct) {
                int ctI = w * 16 + ct;
                u32x4 bf[8];
#pragma unroll
                for (int kt = 0; kt < 8; ++kt)
                    bf[kt] = *(const u32x4*)(Wt1 + (size_t)(ctI * 16 + lr) * DIN + kt * 32 + lg * 8);
                f32x4 acc = f32x4{0.f, 0.f, 0.f, 0.f};
#pragma unroll
                for (int kt = 0; kt < 8; ++kt) {
                    f16x8 af = *(const f16x8*)&ys[lr][kt * 32 + lg * 8];
                    acc = __builtin_amdgcn_mfma_f32_16x16x32_f16(af, asf16(bf[kt]), acc, 0, 0, 0);
                }
                // C: row=(lane>>4)*4+v, col=lane&15 (verified layout)
#pragma unroll
                for (int v = 0; v < 4; ++v) {
                    float z = acc[v] + b1w[ct];
                    __hip_atomic_store(&xzbuf[(size_t)(lg * 4 + v) * G4 + ctI * 16 + lr],
                                       __builtin_bit_cast(uint_t, z),
                                       __ATOMIC_RELAXED, __HIP_MEMORY_SCOPE_AGENT);
                }
            }
            __syncthreads();   // drain stores before flag
            if (tid == 0)
                __hip_atomic_store(f2p, ch + 1, __ATOMIC_RELEASE, __HIP_MEMORY_SCOPE_AGENT);
        }
        return;
    }

    // ---- roles 0,2: preload U fragments (r7 layout) ----
    const u32x4* Upk = (role == 2) ? Upk1 : Upk0;
    u32x4 ua[64];   // kt0-3 -> AGPR
    u32x4 uv[32];   // kt4-5 -> VGPR
#pragma unroll
    for (int gb = 0; gb < 4; ++gb)
#pragma unroll
        for (int ti = 0; ti < 4; ++ti) {
            int col = (gb * 16 + w * 4 + ti) * 16 + lr;
            int fi = gb * 4 + ti;
#pragma unroll
            for (int kt = 0; kt < 4; ++kt)
                ua[fi * 4 + kt] = Upk[(kt * 4 + lg) * 1024 + col];
#pragma unroll
            for (int k2 = 0; k2 < 2; ++k2)
                uv[fi * 2 + k2] = Upk[((4 + k2) * 4 + lg) * 1024 + col];
        }
#pragma unroll
    for (int i = 0; i < 64; ++i) PINA(ua[i]);
#pragma unroll
    for (int i = 0; i < 32; ++i) PINV(uv[i]);

#pragma unroll
    for (int gb = 0; gb < 4; ++gb)
#pragma unroll
        for (int ti = 0; ti < 4; ++ti) {
            int col = (gb * 16 + w * 4 + ti) * 16 + lr;
            int fi = gb * 4 + ti;
#pragma unroll
            for (int k2 = 0; k2 < 2; ++k2)
                Uld[w][k2][fi][l] = Upk[((6 + k2) * 4 + lg) * 1024 + col];
        }

    h16[0][tid] = 0;
    float c = 0.f;

#define STEP_BODY(AF, XZC, ZG)                                                        \
    {                                                                                 \
        _Pragma("unroll")                                                             \
        for (int gb = 0; gb < 4; ++gb) {                                              \
            f32x4 accA[4], accB[4];                                                   \
            _Pragma("unroll")                                                         \
            for (int ti = 0; ti < 4; ++ti) {                                          \
                accA[ti] = f32x4{0.f, 0.f, 0.f, 0.f};                                 \
                accB[ti] = f32x4{0.f, 0.f, 0.f, 0.f};                                 \
            }                                                                         \
            _Pragma("unroll")                                                         \
            for (int ti = 0; ti < 4; ++ti) {                                          \
                int fi = gb * 4 + ti;                                                 \
                _Pragma("unroll")                                                     \
                for (int kt = 0; kt < 4; ++kt)                                        \
                    accA[ti] = __builtin_amdgcn_mfma_f32_16x16x32_f16(                \
                        AF[kt], asf16(ua[fi * 4 + kt]), accA[ti], 0, 0, 0);           \
                _Pragma("unroll")                                                     \
                for (int k2 = 0; k2 < 2; ++k2)                                        \
                    accB[ti] = __builtin_amdgcn_mfma_f32_16x16x32_f16(                \
                        AF[4 + k2], asf16(uv[fi * 2 + k2]), accB[ti], 0, 0, 0);       \
                _Pragma("unroll")                                                     \
                for (int k2 = 0; k2 < 2; ++k2) {                                      \
                    u32x4 ub = Uld[w][k2][fi][l];                                     \
                    accB[ti] = __builtin_amdgcn_mfma_f32_16x16x32_f16(                \
                        AF[6 + k2], asf16(ub), accB[ti], 0, 0, 0);                    \
                }                                                                     \
            }                                                                         \
            float za = (lg == 0) ? accA[0][0] : (lg == 1) ? accA[1][0]                \
                     : (lg == 2) ? accA[2][0] : accA[3][0];                           \
            float zb = (lg == 0) ? accB[0][0] : (lg == 1) ? accB[1][0]                \
                     : (lg == 2) ? accB[2][0] : accB[3][0];                           \
            ZG[gb] = za + zb + XZC[gb];                                               \
        }                                                                             \
    }

    if (role == 0) {
        // ================= layer-1 producer =================
        uint_t* hr = (uint_t*)&ys[0][0];   // [CH][128] packed h ring (8 KB)
        const ushort_t* xz_b = xz1h + (size_t)b * T * G4;
        float xzc[4];
#pragma unroll
        for (int gb = 0; gb < 4; ++gb) xzc[gb] = f16f(xz_b[gb * 256 + hcol]);
        __syncthreads();

        for (int t = 0; t < T; ++t) {
            const int cur = t & 1, nxt = cur ^ 1;

            f16x8 af[8];
#pragma unroll
            for (int kt = 0; kt < 8; ++kt)
                af[kt] = *(const f16x8*)((const char*)&h16[cur][0] + kt * 64 + lg * 16);

            float xzn[4];
            {
                const ushort_t* xztn = xz_b + (size_t)((t + 1 < T) ? (t + 1) : t) * G4;
#pragma unroll
                for (int gb = 0; gb < 4; ++gb) xzn[gb] = f16f(xztn[gb * 256 + hcol]);
            }

            float zg[4];
            STEP_BODY(af, xzc, zg);

            c = sig_(zg[1]) * c + sig_(zg[0]) * tanh_(zg[2]);
            float h = sig_(zg[3]) * tanh_(c);

            h16[nxt][hcol] = f16b(h);
            {
                uint_t hb = (uint_t)f16b(h);
                uint_t pb = (uint_t)(unsigned)__shfl_xor((int)hb, 1);
                if (!(l & 1))
                    hr[(t & (CH - 1)) * 128 + (hcol >> 1)] = hb | (pb << 16);
            }
#pragma unroll
            for (int gb = 0; gb < 4; ++gb) xzc[gb] = xzn[gb];

            __syncthreads();

            if ((t & (CH - 1)) == (CH - 1)) {
                int t0 = t - (CH - 1);
#pragma unroll
                for (int it = 0; it < 8; ++it) {
                    int idx = it * 256 + tid;
                    int row = idx >> 7;
                    int j = idx & 127;
                    __hip_atomic_store(&y1pk[(size_t)(b * T + t0 + row) * 128 + j],
                                       hr[row * 128 + j],
                                       __ATOMIC_RELAXED, __HIP_MEMORY_SCOPE_AGENT);
                }
                __syncthreads();
                if (tid == 0)
                    __hip_atomic_store(f1p, (t + 1) / CH, __ATOMIC_RELEASE,
                                       __HIP_MEMORY_SCOPE_AGENT);
            }
        }
    } else {
        // ================= layer-2 consumer (out-ring + xz2 prefetch) =================
        float* orb = (float*)&ys[0][0];    // [CH][256] f32 out ring (16 KB)
        __syncthreads();

        for (int ch = 0; ch < NCH; ++ch) {
            if (tid == 0) {
                while (__hip_atomic_load(f2p, __ATOMIC_ACQUIRE, __HIP_MEMORY_SCOPE_AGENT) < ch + 1)
                    __builtin_amdgcn_s_sleep(32);
            }
            __syncthreads();

            const uint_t* xzbuf = xz2u + ((size_t)(b * 4 + (ch & 3)) * CH) * G4;
            uint_t xzw[4], xznw[4];

            for (int tb = 0; tb < CH; ++tb) {
                const int t = ch * CH + tb;
                const int cur = t & 1, nxt = cur ^ 1;

                if (tb == 0) {
#pragma unroll
                    for (int gb = 0; gb < 4; ++gb)
                        xzw[gb] = __hip_atomic_load(&xzbuf[gb * 256 + hcol],
                                                    __ATOMIC_RELAXED, __HIP_MEMORY_SCOPE_AGENT);
                } else {
#pragma unroll
                    for (int gb = 0; gb < 4; ++gb) xzw[gb] = xznw[gb];
                }

                f16x8 af[8];
#pragma unroll
                for (int kt = 0; kt < 8; ++kt)
                    af[kt] = *(const f16x8*)((const char*)&h16[cur][0] + kt * 64 + lg * 16);

                // prefetch next step's xz2 (hidden under MFMAs)
                if (tb + 1 < CH) {
#pragma unroll
                    for (int gb = 0; gb < 4; ++gb)
                        xznw[gb] = __hip_atomic_load(
                            &xzbuf[(size_t)(tb + 1) * G4 + gb * 256 + hcol],
                            __ATOMIC_RELAXED, __HIP_MEMORY_SCOPE_AGENT);
                }

                float xzc[4];
#pragma unroll
                for (int gb = 0; gb < 4; ++gb)
                    xzc[gb] = __builtin_bit_cast(float, xzw[gb]);

                float zg[4];
                STEP_BODY(af, xzc, zg);

                c = sig_(zg[1]) * c + sig_(zg[0]) * tanh_(zg[2]);
                float h = sig_(zg[3]) * tanh_(c);

                h16[nxt][hcol] = f16b(h);
                orb[tb * 256 + hcol] = h;      // LDS only — no global drain at barrier

                __syncthreads();
            }

            // one coalesced out dump per chunk (16 KB)
#pragma unroll
            for (int it = 0; it < 16; ++it) {
                int idx = it * 256 + tid;
                int row = idx >> 8;
                int col = idx & 255;
                out[(size_t)(b * T + ch * CH + row) * HID + col] = orb[row * 256 + col];
            }
            if (tid == 0)
                __hip_atomic_store(f3p, ch + 1, __ATOMIC_RELEASE, __HIP_MEMORY_SCOPE_AGENT);
        }
    }
#undef STEP_BODY
}

// ---------------- launch ----------------

extern "C" void kernel_launch(void* const* d_in, const int* in_sizes, int n_in,
                              void* d_out, int out_size, void* d_ws, size_t ws_size,
                              hipStream_t stream) {
    const float* x  = (const float*)d_in[0];
    const float* W0 = (const float*)d_in[1];
    const float* U0 = (const float*)d_in[2];
    const float* b0 = (const float*)d_in[3];
    const float* W1 = (const float*)d_in[4];
    const float* U1 = (const float*)d_in[5];
    const float* b1 = (const float*)d_in[6];
    float* out = (float*)d_out;

    const size_t M = (size_t)BATCH * SEQT;   // 32768

    char* ws = (char*)d_ws;
    ushort_t* xf16  = (ushort_t*)(ws);                         // 16 MB @ 0
    uint_t*   y1pk  = (uint_t*)  (ws + (16u << 20));           // 16 MB @ 16M
    ushort_t* Wt0   = (ushort_t*)(ws + (32u << 20));           // 0.5 MB @ 32M
    ushort_t* Wt1   = (ushort_t*)(ws + (32u << 20) + 524288);  // 0.5 MB
    u32x4*    Upk0  = (u32x4*)   (ws + (33u << 20));           // 0.5 MB @ 33M
    u32x4*    Upk1  = (u32x4*)   (ws + (33u << 20) + 524288);  // 0.5 MB
    int*      flag1 = (int*)     (ws + (34u << 20));           // @34M
    int*      flag2 = (int*)     (ws + (34u << 20) + 65536);
    int*      flag3 = (int*)     (ws + (34u << 20) + 131072);
    uint_t*   xz2u  = (uint_t*)  (ws + (35u << 20));           // 16 MB @ 35M
    ushort_t* xz1h  = (ushort_t*)(ws + (51u << 20));           // 64 MB @ 51M

    // reset handoff flags every launch (graph-replay safe)
    hipMemsetAsync(flag1, 0, 196608, stream);

    // merged prep: cvt_x + Wt0/Wt1 + Upk0/Upk1 (one launch)
    prep_all_kernel<<<dim3(10496), dim3(256), 0, stream>>>(
        x, W0, W1, U0, U1, xf16, Wt0, Wt1, (uint4*)Upk0, (uint4*)Upk1);

    // layer-1 input projection (f16 output)
    gemm_f16_kernel<<<dim3((int)(M / 128) * 8), dim3(256), 0, stream>>>(xf16, Wt0, b0, xz1h, (int)M);

    // 3-stage pipelined recurrence: 64 producers + 64 gemm + 64 consumers
    lstm_pipe3_kernel<<<dim3(192), dim3(256), 0, stream>>>(
        xz1h, Upk0, Upk1, Wt1, b1, y1pk, flag1, flag2, flag3, xz2u, out, SEQT);
}